// Round 21
// baseline (867.482 us; speedup 1.0000x reference)
//
#include <hip/hip_runtime.h>
#include <hip/hip_bf16.h>
#include <type_traits>

#define NN 50000
#define NP 50048   // NN padded to 64*782
#define EE 800000
#define TT 3
#define ED 64
#define NS 23
#define MD 87
#define HH 200
#define NMOL 2048
#define RD 256

#define SP 216     // LDS act hi-plane stride (shorts)
#define NPB2 512   // colstats partial blocks
#define SNB ((NN + 255) / 256)  // 196 scan blocks

typedef __attribute__((ext_vector_type(8))) short short8b;
typedef __attribute__((ext_vector_type(4))) short short4b;
typedef __attribute__((ext_vector_type(4))) float f32x4;

// ---- bf16 helpers ----
__device__ __forceinline__ unsigned short f2bf(float f) {
  unsigned u = __float_as_uint(f);
  return (unsigned short)((u + 0x7fffu + ((u >> 16) & 1u)) >> 16);
}
__device__ __forceinline__ float ubf2f(unsigned short h) {
  return __uint_as_float(((unsigned)h) << 16);
}
// interleaved pair in one u32: low16 = hi-bf16, high16 = lo-bf16 (fp32-equivalent)
__device__ __forceinline__ float bfp2f(unsigned p) {
  return __uint_as_float(p << 16) + __uint_as_float(p & 0xffff0000u);
}
__device__ __forceinline__ unsigned packsplit(float v) {
  unsigned short h = f2bf(v);
  unsigned short l = f2bf(v - ubf2f(h));
  return (unsigned)h | ((unsigned)l << 16);
}

// ---------------- weight prep: fp32 [T][K][N] -> PACKED fragment-major planes -----
// Packed layout: per (tile of 16 n-rows, kblk of 32 cols): 1024 shorts =
// [512 hi][512 lo], lane-linear (slot = lane*8+e, lane = quad*16+ln,
// n = tile*16+ln, k = kblk*32+quad*8+e). B-frag load = ONE coalesced 1KB burst.
struct WD { const float* src; short* dst; int K, N, Kpad, Npad, T; };
struct WDs { WD d[5]; };

__global__ __launch_bounds__(256) void wprep_kernel(WDs W) {
  WD w = W.d[blockIdx.y];
  int KB = w.Kpad >> 5, NT = w.Npad >> 4;
  int per = w.Npad * w.Kpad;  // == NT*KB*512
  int total = w.T * per;
  for (int idx = blockIdx.x * 256 + threadIdx.x; idx < total; idx += gridDim.x * 256) {
    int t = idx / per;
    int r = idx - t * per;
    int e = r & 7, lane = (r >> 3) & 63;
    int blk = r >> 9;
    int kb = blk % KB, tile = blk / KB;
    int ln = lane & 15, quad = lane >> 4;
    int n = tile * 16 + ln, k = kb * 32 + quad * 8 + e;
    float v = 0.f;
    if (k < w.K && n < w.N) v = w.src[((size_t)t * w.K + k) * w.N + n];
    unsigned short h = f2bf(v);
    unsigned short l = f2bf(v - ubf2f(h));
    size_t base = ((size_t)(t * NT + tile) * KB + kb) * 1024;
    w.dst[base + lane * 8 + e] = (short)h;
    w.dst[base + 512 + lane * 8 + e] = (short)l;
  }
}

// ---------------- fused BN-finalize + layer-1 weight scale (packed output) ----
// na/nb are consumed ONLY here, so the per-column stat finalize (was bnfinal2)
// is folded in: thread k reduces column k of P (512 coalesced independent
// loads, L2-resident), computes na/nb, scales W. bc[n] = b[n] + sum_k nb_k*W.
__global__ __launch_bounds__(256) void wscale_kernel(const float* __restrict__ wsrc,
                                                     const float* __restrict__ P, int nblk,
                                                     const float* __restrict__ g,
                                                     const float* __restrict__ b,
                                                     const float* __restrict__ bsrc,
                                                     int K, int Kpad, int ncols,
                                                     short* __restrict__ wsp,
                                                     float* __restrict__ bc) {
  int n = blockIdx.x;   // 0..207
  int k = threadIdx.x;  // 0..255
  int KB = Kpad >> 5;
  int tile = n >> 4, ln = n & 15;
  float na_k = 0.f, nb_k = 0.f;
  if (k < ncols) {
    float s0 = 0.f, s1 = 0.f, q0 = 0.f, q1 = 0.f;
    for (int i = 0; i + 2 <= nblk; i += 2) {
      s0 += P[(size_t)i * 512 + k];
      s1 += P[(size_t)(i + 1) * 512 + k];
      q0 += P[(size_t)i * 512 + 256 + k];
      q1 += P[(size_t)(i + 1) * 512 + 256 + k];
    }
    float s = s0 + s1, q = q0 + q1;
    float mean = s / (float)NN;
    float var = q / (float)NN - mean * mean;
    na_k = g[k] * rsqrtf(var + 1e-5f);
    nb_k = b[k] - mean * na_k;
  }
  float contrib = 0.f;
  if (k < Kpad) {
    float v = 0.f;
    if (n < HH && k < K) {
      float w = wsrc[(size_t)k * HH + n];
      v = na_k * w;
      contrib = nb_k * w;
    }
    unsigned short h = f2bf(v);
    unsigned short l = f2bf(v - ubf2f(h));
    int kb = k >> 5, quad = (k & 31) >> 3, e = k & 7;
    int lane = quad * 16 + ln;
    size_t base = ((size_t)tile * KB + kb) * 1024;
    wsp[base + lane * 8 + e] = (short)h;
    wsp[base + 512 + lane * 8 + e] = (short)l;
  }
  __shared__ float sh[256];
  sh[k] = contrib;
  __syncthreads();
  for (int off = 128; off > 0; off >>= 1) {
    if (k < off) sh[k] += sh[k + off];
    __syncthreads();
  }
  if (k == 0) bc[n] = (n < HH ? bsrc[n] : 0.f) + sh[0];
}

// ---------------- embedding -> x slice 0 (pair + row plane + slice plane) ----
__global__ __launch_bounds__(256) void emb_kernel(const int* __restrict__ z,
                                                  const float* __restrict__ emb,
                                                  unsigned* __restrict__ xp,
                                                  short* __restrict__ xq,
                                                  short* __restrict__ xqs) {
  int idx = blockIdx.x * 256 + threadIdx.x;
  if (idx >= NN * ED) return;
  int i = idx >> 6, d = idx & 63;
  unsigned pk = packsplit(emb[z[i] * ED + d]);
  xp[(size_t)i * RD + d] = pk;
  short h = (short)(pk & 0xffffu);
  xq[(size_t)i * RD + d] = h;
  xqs[(size_t)i * ED + d] = h;  // slice 0
}

// ---------------- CSR build ----------------
__global__ __launch_bounds__(256) void hist_kernel(const int* __restrict__ src,
                                                   int* __restrict__ deg) {
  int e = blockIdx.x * 256 + threadIdx.x;
  if (e < EE) atomicAdd(&deg[src[e]], 1);
}

// 3-stage parallel exclusive scan of deg[0..NN)
__global__ __launch_bounds__(256) void scanA_kernel(const int* __restrict__ deg,
                                                    int* __restrict__ Psum) {
  int i = blockIdx.x * 256 + threadIdx.x;
  int v = (i < NN) ? deg[i] : 0;
#pragma unroll
  for (int off = 32; off > 0; off >>= 1) v += __shfl_down(v, off, 64);
  __shared__ int ws[4];
  if ((threadIdx.x & 63) == 0) ws[threadIdx.x >> 6] = v;
  __syncthreads();
  if (threadIdx.x == 0) Psum[blockIdx.x] = ws[0] + ws[1] + ws[2] + ws[3];
}

__global__ __launch_bounds__(256) void scanB_kernel(const int* __restrict__ Psum,
                                                    int* __restrict__ Poff) {
  __shared__ int sh[256];
  int t = threadIdx.x;
  int v = (t < SNB) ? Psum[t] : 0;
  sh[t] = v;
  __syncthreads();
  for (int off = 1; off < 256; off <<= 1) {
    int u = (t >= off) ? sh[t - off] : 0;
    __syncthreads();
    sh[t] += u;
    __syncthreads();
  }
  if (t < SNB) Poff[t] = sh[t] - v;  // exclusive
}

__global__ __launch_bounds__(256) void scanC_kernel(const int* __restrict__ deg,
                                                    const int* __restrict__ Poff,
                                                    int* __restrict__ offs,
                                                    int* __restrict__ cursor) {
  __shared__ int sh[256];
  int t = threadIdx.x;
  int i = blockIdx.x * 256 + t;
  int v = (i < NN) ? deg[i] : 0;
  sh[t] = v;
  __syncthreads();
  for (int off = 1; off < 256; off <<= 1) {
    int u = (t >= off) ? sh[t - off] : 0;
    __syncthreads();
    sh[t] += u;
    __syncthreads();
  }
  int excl = Poff[blockIdx.x] + sh[t] - v;
  if (i < NN) {
    offs[i] = excl;
    cursor[i] = excl;
    if (i == NN - 1) offs[NN] = excl + v;
  }
}

__global__ __launch_bounds__(256) void scatter_kernel(const int* __restrict__ src,
                                                      const int* __restrict__ snk,
                                                      const float* __restrict__ dist,
                                                      int* __restrict__ cursor,
                                                      int* __restrict__ ssink,
                                                      float* __restrict__ sdist) {
  int e = blockIdx.x * 256 + threadIdx.x;
  if (e >= EE) return;
  int p = atomicAdd(&cursor[src[e]], 1);
  ssink[p] = snk[e];
  sdist[p] = dist[e];
}

// ---------------- message gather: one wave per node ----------------
// Reads SLICE-MAJOR xqs (6.4 MB working set -> L2-resident). RBF sums
// (m cols 0..22) are pass-invariant: computed only at t=0.
template <bool RBF>
__global__ __launch_bounds__(256) void gather_kernel(const int* __restrict__ offs,
                                                     const int* __restrict__ ssink,
                                                     const float* __restrict__ sdist,
                                                     const short* __restrict__ xqs,
                                                     short* __restrict__ mh) {
  int node = blockIdx.x * 4 + (threadIdx.x >> 6);
  int lane = threadIdx.x & 63;
  if (node >= NN) return;
  float shift = (float)(0.8 + 0.1 * (double)lane);
  int e0 = offs[node], e1 = offs[node + 1];
  float ax0 = 0.f, ax1 = 0.f, ar0 = 0.f, ar1 = 0.f;
  int j = e0;
  for (; j + 4 <= e1; j += 4) {
    int s0 = ssink[j], s1 = ssink[j + 1], s2 = ssink[j + 2], s3 = ssink[j + 3];
    float x0 = ubf2f((unsigned short)xqs[(size_t)s0 * ED + lane]);
    float x1 = ubf2f((unsigned short)xqs[(size_t)s1 * ED + lane]);
    float x2 = ubf2f((unsigned short)xqs[(size_t)s2 * ED + lane]);
    float x3 = ubf2f((unsigned short)xqs[(size_t)s3 * ED + lane]);
    ax0 += x0 + x2;
    ax1 += x1 + x3;
    if (RBF && lane < NS) {
      float d0 = sdist[j], d1 = sdist[j + 1], d2 = sdist[j + 2], d3 = sdist[j + 3];
      float u0 = d0 - shift, u1 = d1 - shift, u2 = d2 - shift, u3 = d3 - shift;
      ar0 += __expf(-u0 * u0) + __expf(-u2 * u2);
      ar1 += __expf(-u1 * u1) + __expf(-u3 * u3);
    }
  }
  for (; j < e1; j++) {
    int s = ssink[j];
    ax0 += ubf2f((unsigned short)xqs[(size_t)s * ED + lane]);
    if (RBF && lane < NS) {
      float u = sdist[j] - shift;
      ar0 += __expf(-u * u);
    }
  }
  float accx = ax0 + ax1;
  if (RBF && lane < NS) mh[(size_t)node * 96 + lane] = (short)f2bf(ar0 + ar1);
  mh[(size_t)node * 96 + NS + lane] = (short)f2bf(accx);
}

// ---------------- batchnorm stats on bf16 planes (vectorized, 512 blocks) ----
template <int LD>
__global__ __launch_bounds__(256) void colstats_s16_kernel(const short* __restrict__ X,
                                                           float* __restrict__ P) {
  constexpr int CG = LD / 8;     // 8-col groups
  constexpr int RPB = 256 / CG;
  const int t = threadIdx.x;
  const int cg = t % CG, rin = t / CG;
  float s[8] = {0, 0, 0, 0, 0, 0, 0, 0}, q[8] = {0, 0, 0, 0, 0, 0, 0, 0};
  if (rin < RPB) {
    for (int r = blockIdx.x * RPB + rin; r < NN; r += gridDim.x * RPB) {
      union { uint4 v; short e[8]; } u;
      u.v = *(const uint4*)(X + (size_t)r * LD + cg * 8);
#pragma unroll
      for (int e = 0; e < 8; e++) {
        float f = ubf2f((unsigned short)u.e[e]);
        s[e] += f;
        q[e] += f * f;
      }
    }
  }
  __shared__ float sh[256][16];
#pragma unroll
  for (int e = 0; e < 8; e++) { sh[t][e] = s[e]; sh[t][8 + e] = q[e]; }
  __syncthreads();
  if (rin == 0) {
    for (int rr = 1; rr < RPB; rr++) {
      const float* o = sh[rr * CG + cg];
#pragma unroll
      for (int e = 0; e < 8; e++) { s[e] += o[e]; q[e] += o[8 + e]; }
    }
    float* Pb = P + blockIdx.x * 512;
#pragma unroll
    for (int e = 0; e < 8; e++) {
      Pb[cg * 8 + e] = s[e];
      Pb[256 + cg * 8 + e] = q[e];
    }
  }
}

// ---------------- fused MLP kernel (packed-B, mixed terms, unrolled K) -------
template <bool READOUT>
__global__ __launch_bounds__(512, 4) void fused_kernel(
    const short* __restrict__ Agh, int glda,
    const short* __restrict__ W1p,
    const short* __restrict__ W2p, const short* __restrict__ W3p,
    const short* __restrict__ W4p,
    const float* __restrict__ b1, const float* __restrict__ b2,
    const float* __restrict__ b3, const float* __restrict__ b4,
    unsigned* __restrict__ xp, short* __restrict__ xq, short* __restrict__ xqs,
    int t, const float* __restrict__ w4ro, const int* __restrict__ mol,
    float* __restrict__ out) {
  __shared__ short ldsH[64 * SP + 16];
  const int tid = threadIdx.x;
  const int wave = tid >> 6, lane = tid & 63, ln = lane & 15, quad = lane >> 4;
  const int bm = blockIdx.x * 64;
  const int ntile = (wave < 5) ? 2 : 1;
  const int tile0 = (wave < 5) ? 2 * wave : wave + 5;  // 13 tiles of 16
  const int n0col = tile0 * 16;

  if (tid < 16) ldsH[64 * SP + tid] = 0;  // zero tail for row-63 k-overread

  f32x4 acc[4][2];

  // KB/KP compile-time -> full unroll lets the scheduler batch B bursts.
  auto layer = [&](auto ga_tag, auto terms_tag, auto kb_tag, auto kp_tag,
                   const short* __restrict__ Wp) {
    constexpr bool GA = decltype(ga_tag)::value;
    constexpr int TERMS = decltype(terms_tag)::value;
    constexpr int KB = decltype(kb_tag)::value;
    constexpr int KP = decltype(kp_tag)::value;
    (void)KB;
#pragma unroll
    for (int i = 0; i < 4; i++)
#pragma unroll
      for (int j = 0; j < 2; j++) acc[i][j] = (f32x4){0.f, 0.f, 0.f, 0.f};
#pragma unroll
    for (int k0 = 0; k0 < KP; k0 += 32) {
      const int kb = k0 >> 5;
      short8b ah[4], bh[2], bl[2];
#pragma unroll
      for (int i = 0; i < 4; i++) {
        int r = i * 16 + ln;
        if constexpr (GA)
          ah[i] = *(const short8b*)(Agh + (size_t)(bm + r) * glda + k0 + quad * 8);
        else
          ah[i] = *(const short8b*)(ldsH + r * SP + k0 + quad * 8);
      }
#pragma unroll
      for (int j = 0; j < 2; j++)
        if (j < ntile) {
          const short* bp = Wp + ((size_t)((tile0 + j) * KB + kb)) * 1024 + lane * 8;
          bh[j] = *(const short8b*)bp;
          if constexpr (TERMS == 2) bl[j] = *(const short8b*)(bp + 512);
        }
#pragma unroll
      for (int j = 0; j < 2; j++)
        if (j < ntile)
#pragma unroll
          for (int i = 0; i < 4; i++) {
            acc[i][j] = __builtin_amdgcn_mfma_f32_16x16x32_bf16(ah[i], bh[j], acc[i][j], 0, 0, 0);
            if constexpr (TERMS == 2)
              acc[i][j] =
                  __builtin_amdgcn_mfma_f32_16x16x32_bf16(ah[i], bl[j], acc[i][j], 0, 0, 0);
          }
    }
  };

  // epilogue: relu(acc+bias) -> hi plane; zero cols [208,216) of every row
  auto epi = [&](const float* __restrict__ bias) {
    __syncthreads();
#pragma unroll
    for (int i = 0; i < 4; i++)
#pragma unroll
      for (int j = 0; j < 2; j++)
        if (j < ntile)
#pragma unroll
          for (int r = 0; r < 4; r++) {
            int row = i * 16 + quad * 4 + r;
            int col = n0col + j * 16 + ln;
            float v = acc[i][j][r] + (col < HH ? bias[col] : 0.f);
            v = fmaxf(v, 0.f);
            ldsH[row * SP + col] = (short)f2bf(v);
          }
    // NaN guard: cols 208..215 (8 threads/row x 1 short, 512 thr = 64 rows)
    ldsH[(tid >> 3) * SP + 208 + (tid & 7)] = 0;
    __syncthreads();
  };

  using one_t = std::integral_constant<int, 1>;
  using two_t = std::integral_constant<int, 2>;

  if (!READOUT) {
    layer(std::true_type{}, two_t{}, std::integral_constant<int, 3>{},
          std::integral_constant<int, 96>{}, W1p);
    epi(b1);
    layer(std::false_type{}, one_t{}, std::integral_constant<int, 7>{},
          std::integral_constant<int, 224>{}, W2p);
    epi(b2);
    layer(std::false_type{}, one_t{}, std::integral_constant<int, 7>{},
          std::integral_constant<int, 224>{}, W3p);
    epi(b3);
    // ---- L4 (200->64): 2M x 4N wave split, packed B, 2-term ----
    const int wm4 = wave & 1, wn4 = wave >> 1;  // rows wm4*32.., col tile wn4
    f32x4 a4[2];
#pragma unroll
    for (int i = 0; i < 2; i++) a4[i] = (f32x4){0.f, 0.f, 0.f, 0.f};
#pragma unroll
    for (int k0 = 0; k0 < 224; k0 += 32) {
      const int kb = k0 >> 5;
      short8b ah[2], bh, bl;
#pragma unroll
      for (int i = 0; i < 2; i++) {
        int r = wm4 * 32 + i * 16 + ln;
        ah[i] = *(const short8b*)(ldsH + r * SP + k0 + quad * 8);
      }
      const short* bp = W4p + ((size_t)(wn4 * 7 + kb)) * 1024 + lane * 8;
      bh = *(const short8b*)bp;
      bl = *(const short8b*)(bp + 512);
#pragma unroll
      for (int i = 0; i < 2; i++) {
        a4[i] = __builtin_amdgcn_mfma_f32_16x16x32_bf16(ah[i], bh, a4[i], 0, 0, 0);
        a4[i] = __builtin_amdgcn_mfma_f32_16x16x32_bf16(ah[i], bl, a4[i], 0, 0, 0);
      }
    }
    // x-update: x[t+1] = x[t] + 0.1*(h3@W4 + b4); maintain row plane + slice plane
#pragma unroll
    for (int i = 0; i < 2; i++)
#pragma unroll
      for (int r = 0; r < 4; r++) {
        int grow = bm + wm4 * 32 + i * 16 + quad * 4 + r;
        int col = wn4 * 16 + ln;
        if (grow < NN) {
          float v = a4[i][r] + b4[col];
          size_t base = (size_t)grow * RD;
          float old = bfp2f(xp[base + (size_t)t * ED + col]);
          unsigned pk = packsplit(old + 0.1f * v);
          xp[base + (size_t)(t + 1) * ED + col] = pk;
          short h = (short)(pk & 0xffffu);
          xq[base + (size_t)(t + 1) * ED + col] = h;
          xqs[(size_t)(t + 1) * NN * ED + (size_t)grow * ED + col] = h;
        }
      }
  } else {
    layer(std::true_type{}, two_t{}, std::integral_constant<int, 8>{},
          std::integral_constant<int, 256>{}, W1p);
    epi(b1);
    layer(std::false_type{}, one_t{}, std::integral_constant<int, 7>{},
          std::integral_constant<int, 224>{}, W2p);
    epi(b2);
    layer(std::false_type{}, one_t{}, std::integral_constant<int, 7>{},
          std::integral_constant<int, 224>{}, W3p);
    epi(b3);
    // fused final layer (200->1) + molecule segment-sum: 8 threads per row
    int row = tid >> 3;
    int grow = bm + row;
    float s = 0.f;
    for (int c = (tid & 7); c < HH; c += 8)
      s += ubf2f((unsigned short)ldsH[row * SP + c]) * w4ro[c];
    s += __shfl_xor(s, 1, 64);
    s += __shfl_xor(s, 2, 64);
    s += __shfl_xor(s, 4, 64);
    if ((tid & 7) == 0 && grow < NN) atomicAdd(&out[mol[grow]], s + b4[0]);
  }
}

// ---------------- host launcher ----------------
extern "C" void kernel_launch(void* const* d_in, const int* in_sizes, int n_in,
                              void* d_out, int out_size, void* d_ws, size_t ws_size,
                              hipStream_t stream) {
  const int* z_i = (const int*)d_in[0];
  const int* e_src = (const int*)d_in[1];
  const int* e_snk = ((const int*)d_in[1]) + EE;
  const float* dist = (const float*)d_in[2];
  const int* mol = (const int*)d_in[3];
  const float* emb = (const float*)d_in[4];
  const float* up_bn_g = (const float*)d_in[5];
  const float* up_bn_b = (const float*)d_in[6];
  const float* up_w1 = (const float*)d_in[7];
  const float* up_b1 = (const float*)d_in[8];
  const float* up_w2 = (const float*)d_in[9];
  const float* up_b2 = (const float*)d_in[10];
  const float* up_w3 = (const float*)d_in[11];
  const float* up_b3 = (const float*)d_in[12];
  const float* up_w4 = (const float*)d_in[13];
  const float* up_b4 = (const float*)d_in[14];
  const float* ro_bn_g = (const float*)d_in[15];
  const float* ro_bn_b = (const float*)d_in[16];
  const float* ro_w1 = (const float*)d_in[17];
  const float* ro_b1 = (const float*)d_in[18];
  const float* ro_w2 = (const float*)d_in[19];
  const float* ro_b2 = (const float*)d_in[20];
  const float* ro_w3 = (const float*)d_in[21];
  const float* ro_b3 = (const float*)d_in[22];
  const float* ro_w4 = (const float*)d_in[23];
  const float* ro_b4 = (const float*)d_in[24];
  float* out = (float*)d_out;

  char* p = (char*)d_ws;
  auto alloc = [&](size_t bytes) {
    void* r = (void*)p;
    p += (bytes + 255) & ~(size_t)255;
    return r;
  };
  unsigned* x_p = (unsigned*)alloc((size_t)NN * RD * 4);     // fp32-equiv pair
  short* x_q = (short*)alloc((size_t)NP * RD * 2);           // x hi plane (row-major)
  short* x_qs = (short*)alloc((size_t)(TT + 1) * NN * ED * 2);  // x hi SLICE-major (gather)
  short* mh = (short*)alloc((size_t)NP * 96 * 2);            // raw m hi plane
  int* ssink = (int*)alloc((size_t)EE * 4);
  float* sdist = (float*)alloc((size_t)EE * 4);
  int* offs = (int*)alloc((size_t)(NN + 1) * 4);
  int* deg = (int*)alloc((size_t)NN * 4);
  int* cursor = (int*)alloc((size_t)NN * 4);
  int* Psum = (int*)alloc((size_t)SNB * 4);
  int* Poff = (int*)alloc((size_t)SNB * 4);
  float* P = (float*)alloc((size_t)NPB2 * 512 * 4);
  float* b1c = (float*)alloc(208 * 4);
  // packed layer-1 (BN-scaled per pass / readout)
  short* w1sp = (short*)alloc((size_t)13 * 3 * 1024 * 2);
  short* r1sp = (short*)alloc((size_t)13 * 8 * 1024 * 2);
  // packed static weights
  short* w2p = (short*)alloc((size_t)TT * 13 * 7 * 1024 * 2);
  short* w3p = (short*)alloc((size_t)TT * 13 * 7 * 1024 * 2);
  short* w4p = (short*)alloc((size_t)TT * 4 * 7 * 1024 * 2);
  short* r2p = (short*)alloc((size_t)13 * 7 * 1024 * 2);
  short* r3p = (short*)alloc((size_t)13 * 7 * 1024 * 2);

  hipMemsetAsync(deg, 0, (size_t)NN * 4, stream);
  hipMemsetAsync(out, 0, (size_t)NMOL * 4, stream);

  WDs descs;
  descs.d[0] = {up_w2, w2p, HH, HH, 224, 208, TT};
  descs.d[1] = {up_w3, w3p, HH, HH, 224, 208, TT};
  descs.d[2] = {up_w4, w4p, HH, ED, 224, 64, TT};
  descs.d[3] = {ro_w2, r2p, HH, HH, 224, 208, 1};
  descs.d[4] = {ro_w3, r3p, HH, HH, 224, 208, 1};
  wprep_kernel<<<dim3(546, 5), 256, 0, stream>>>(descs);

  emb_kernel<<<(NN * ED + 255) / 256, 256, 0, stream>>>(z_i, emb, x_p, x_q, x_qs);
  hist_kernel<<<(EE + 255) / 256, 256, 0, stream>>>(e_src, deg);
  scanA_kernel<<<SNB, 256, 0, stream>>>(deg, Psum);
  scanB_kernel<<<1, 256, 0, stream>>>(Psum, Poff);
  scanC_kernel<<<SNB, 256, 0, stream>>>(deg, Poff, offs, cursor);
  scatter_kernel<<<(EE + 255) / 256, 256, 0, stream>>>(e_src, e_snk, dist, cursor, ssink, sdist);

  const int gM = NP / 64;  // 782

  for (int t = 0; t < TT; t++) {
    if (t == 0)
      gather_kernel<true><<<(NN + 3) / 4, 256, 0, stream>>>(
          offs, ssink, sdist, x_qs, mh);
    else
      gather_kernel<false><<<(NN + 3) / 4, 256, 0, stream>>>(
          offs, ssink, sdist, x_qs + (size_t)t * NN * ED, mh);
    colstats_s16_kernel<96><<<NPB2, 256, 0, stream>>>(mh, P);
    wscale_kernel<<<208, 256, 0, stream>>>(up_w1 + (size_t)t * MD * HH, P, NPB2,
                                           up_bn_g + t * MD, up_bn_b + t * MD,
                                           up_b1 + t * HH, MD, 96, MD, w1sp, b1c);
    fused_kernel<false><<<gM, 512, 0, stream>>>(
        mh, 96, w1sp,
        w2p + (size_t)t * 13 * 7 * 1024, w3p + (size_t)t * 13 * 7 * 1024,
        w4p + (size_t)t * 4 * 7 * 1024,
        b1c, up_b2 + t * HH, up_b3 + t * HH, up_b4 + t * ED,
        x_p, x_q, x_qs, t, nullptr, nullptr, nullptr);
  }

  colstats_s16_kernel<256><<<NPB2, 256, 0, stream>>>(x_q, P);
  wscale_kernel<<<208, 256, 0, stream>>>(ro_w1, P, NPB2, ro_bn_g, ro_bn_b,
                                         ro_b1, RD, 256, RD, r1sp, b1c);
  fused_kernel<true><<<gM, 512, 0, stream>>>(
      x_q, 256, r1sp,
      r2p, r3p, nullptr,
      b1c, ro_b2, ro_b3, ro_b4,
      nullptr, nullptr, nullptr, 0, ro_w4, mol, out);

  (void)in_sizes; (void)n_in; (void)out_size; (void)ws_size;
}

// Round 22
// 600.697 us; speedup vs baseline: 1.4441x; 1.4441x over previous
//
#include <hip/hip_runtime.h>
#include <hip/hip_bf16.h>
#include <type_traits>

#define NN 50000
#define NP 50048   // NN padded to 64*782
#define EE 800000
#define TT 3
#define ED 64
#define NS 23
#define MD 87
#define HH 200
#define NMOL 2048
#define RD 256

#define SP 216     // LDS act hi-plane stride (shorts)
#define NPB2 512   // colstats partial blocks
#define SNB ((NN + 255) / 256)  // 196 scan blocks

typedef __attribute__((ext_vector_type(8))) short short8b;
typedef __attribute__((ext_vector_type(4))) short short4b;
typedef __attribute__((ext_vector_type(4))) float f32x4;

// ---- bf16 helpers ----
__device__ __forceinline__ unsigned short f2bf(float f) {
  unsigned u = __float_as_uint(f);
  return (unsigned short)((u + 0x7fffu + ((u >> 16) & 1u)) >> 16);
}
__device__ __forceinline__ float ubf2f(unsigned short h) {
  return __uint_as_float(((unsigned)h) << 16);
}
// interleaved pair in one u32: low16 = hi-bf16, high16 = lo-bf16 (fp32-equivalent)
__device__ __forceinline__ float bfp2f(unsigned p) {
  return __uint_as_float(p << 16) + __uint_as_float(p & 0xffff0000u);
}
__device__ __forceinline__ unsigned packsplit(float v) {
  unsigned short h = f2bf(v);
  unsigned short l = f2bf(v - ubf2f(h));
  return (unsigned)h | ((unsigned)l << 16);
}

// ---------------- weight prep: fp32 [T][K][N] -> PACKED fragment-major planes -----
// Packed layout: per (tile of 16 n-rows, kblk of 32 cols): 1024 shorts =
// [512 hi][512 lo], lane-linear (slot = lane*8+e, lane = quad*16+ln,
// n = tile*16+ln, k = kblk*32+quad*8+e). B-frag load = ONE coalesced 1KB burst.
struct WD { const float* src; short* dst; int K, N, Kpad, Npad, T; };
struct WDs { WD d[5]; };

__global__ __launch_bounds__(256) void wprep_kernel(WDs W) {
  WD w = W.d[blockIdx.y];
  int KB = w.Kpad >> 5, NT = w.Npad >> 4;
  int per = w.Npad * w.Kpad;  // == NT*KB*512
  int total = w.T * per;
  for (int idx = blockIdx.x * 256 + threadIdx.x; idx < total; idx += gridDim.x * 256) {
    int t = idx / per;
    int r = idx - t * per;
    int e = r & 7, lane = (r >> 3) & 63;
    int blk = r >> 9;
    int kb = blk % KB, tile = blk / KB;
    int ln = lane & 15, quad = lane >> 4;
    int n = tile * 16 + ln, k = kb * 32 + quad * 8 + e;
    float v = 0.f;
    if (k < w.K && n < w.N) v = w.src[((size_t)t * w.K + k) * w.N + n];
    unsigned short h = f2bf(v);
    unsigned short l = f2bf(v - ubf2f(h));
    size_t base = ((size_t)(t * NT + tile) * KB + kb) * 1024;
    w.dst[base + lane * 8 + e] = (short)h;
    w.dst[base + 512 + lane * 8 + e] = (short)l;
  }
}

// ---------------- BN-folded layer-1 weight scale (packed output) ----------------
// R21 lesson: do NOT fold the P reduction in here (208 blocks each re-read the
// full 1MB P = 208x redundant traffic, +280us). bnfinal2 reduces P once.
__global__ __launch_bounds__(256) void wscale_kernel(const float* __restrict__ wsrc,
                                                     const float* __restrict__ na,
                                                     const float* __restrict__ nb,
                                                     const float* __restrict__ bsrc,
                                                     int K, int Kpad,
                                                     short* __restrict__ wsp,
                                                     float* __restrict__ bc) {
  int n = blockIdx.x;   // 0..207
  int k = threadIdx.x;  // 0..255
  int KB = Kpad >> 5;
  int tile = n >> 4, ln = n & 15;
  float contrib = 0.f;
  if (k < Kpad) {
    float v = 0.f;
    if (n < HH && k < K) {
      float w = wsrc[(size_t)k * HH + n];
      v = na[k] * w;
      contrib = nb[k] * w;
    }
    unsigned short h = f2bf(v);
    unsigned short l = f2bf(v - ubf2f(h));
    int kb = k >> 5, quad = (k & 31) >> 3, e = k & 7;
    int lane = quad * 16 + ln;
    size_t base = ((size_t)tile * KB + kb) * 1024;
    wsp[base + lane * 8 + e] = (short)h;
    wsp[base + 512 + lane * 8 + e] = (short)l;
  }
  __shared__ float sh[256];
  sh[k] = contrib;
  __syncthreads();
  for (int off = 128; off > 0; off >>= 1) {
    if (k < off) sh[k] += sh[k + off];
    __syncthreads();
  }
  if (k == 0) bc[n] = (n < HH ? bsrc[n] : 0.f) + sh[0];
}

// ---------------- embedding -> x slice 0 (pair + row plane + slice plane) ----
__global__ __launch_bounds__(256) void emb_kernel(const int* __restrict__ z,
                                                  const float* __restrict__ emb,
                                                  unsigned* __restrict__ xp,
                                                  short* __restrict__ xq,
                                                  short* __restrict__ xqs) {
  int idx = blockIdx.x * 256 + threadIdx.x;
  if (idx >= NN * ED) return;
  int i = idx >> 6, d = idx & 63;
  unsigned pk = packsplit(emb[z[i] * ED + d]);
  xp[(size_t)i * RD + d] = pk;
  short h = (short)(pk & 0xffffu);
  xq[(size_t)i * RD + d] = h;
  xqs[(size_t)i * ED + d] = h;  // slice 0
}

// ---------------- CSR build ----------------
__global__ __launch_bounds__(256) void hist_kernel(const int* __restrict__ src,
                                                   int* __restrict__ deg) {
  int e = blockIdx.x * 256 + threadIdx.x;
  if (e < EE) atomicAdd(&deg[src[e]], 1);
}

// 3-stage parallel exclusive scan of deg[0..NN)
__global__ __launch_bounds__(256) void scanA_kernel(const int* __restrict__ deg,
                                                    int* __restrict__ Psum) {
  int i = blockIdx.x * 256 + threadIdx.x;
  int v = (i < NN) ? deg[i] : 0;
#pragma unroll
  for (int off = 32; off > 0; off >>= 1) v += __shfl_down(v, off, 64);
  __shared__ int ws[4];
  if ((threadIdx.x & 63) == 0) ws[threadIdx.x >> 6] = v;
  __syncthreads();
  if (threadIdx.x == 0) Psum[blockIdx.x] = ws[0] + ws[1] + ws[2] + ws[3];
}

__global__ __launch_bounds__(256) void scanB_kernel(const int* __restrict__ Psum,
                                                    int* __restrict__ Poff) {
  __shared__ int sh[256];
  int t = threadIdx.x;
  int v = (t < SNB) ? Psum[t] : 0;
  sh[t] = v;
  __syncthreads();
  for (int off = 1; off < 256; off <<= 1) {
    int u = (t >= off) ? sh[t - off] : 0;
    __syncthreads();
    sh[t] += u;
    __syncthreads();
  }
  if (t < SNB) Poff[t] = sh[t] - v;  // exclusive
}

__global__ __launch_bounds__(256) void scanC_kernel(const int* __restrict__ deg,
                                                    const int* __restrict__ Poff,
                                                    int* __restrict__ offs,
                                                    int* __restrict__ cursor) {
  __shared__ int sh[256];
  int t = threadIdx.x;
  int i = blockIdx.x * 256 + t;
  int v = (i < NN) ? deg[i] : 0;
  sh[t] = v;
  __syncthreads();
  for (int off = 1; off < 256; off <<= 1) {
    int u = (t >= off) ? sh[t - off] : 0;
    __syncthreads();
    sh[t] += u;
    __syncthreads();
  }
  int excl = Poff[blockIdx.x] + sh[t] - v;
  if (i < NN) {
    offs[i] = excl;
    cursor[i] = excl;
    if (i == NN - 1) offs[NN] = excl + v;
  }
}

__global__ __launch_bounds__(256) void scatter_kernel(const int* __restrict__ src,
                                                      const int* __restrict__ snk,
                                                      const float* __restrict__ dist,
                                                      int* __restrict__ cursor,
                                                      int* __restrict__ ssink,
                                                      float* __restrict__ sdist) {
  int e = blockIdx.x * 256 + threadIdx.x;
  if (e >= EE) return;
  int p = atomicAdd(&cursor[src[e]], 1);
  ssink[p] = snk[e];
  sdist[p] = dist[e];
}

// ---------------- message gather: one wave per node ----------------
// Reads SLICE-MAJOR xqs (6.4 MB working set -> L2-resident). RBF sums
// (m cols 0..22) are pass-invariant: computed only at t=0.
template <bool RBF>
__global__ __launch_bounds__(256) void gather_kernel(const int* __restrict__ offs,
                                                     const int* __restrict__ ssink,
                                                     const float* __restrict__ sdist,
                                                     const short* __restrict__ xqs,
                                                     short* __restrict__ mh) {
  int node = blockIdx.x * 4 + (threadIdx.x >> 6);
  int lane = threadIdx.x & 63;
  if (node >= NN) return;
  float shift = (float)(0.8 + 0.1 * (double)lane);
  int e0 = offs[node], e1 = offs[node + 1];
  float ax0 = 0.f, ax1 = 0.f, ar0 = 0.f, ar1 = 0.f;
  int j = e0;
  for (; j + 4 <= e1; j += 4) {
    int s0 = ssink[j], s1 = ssink[j + 1], s2 = ssink[j + 2], s3 = ssink[j + 3];
    float x0 = ubf2f((unsigned short)xqs[(size_t)s0 * ED + lane]);
    float x1 = ubf2f((unsigned short)xqs[(size_t)s1 * ED + lane]);
    float x2 = ubf2f((unsigned short)xqs[(size_t)s2 * ED + lane]);
    float x3 = ubf2f((unsigned short)xqs[(size_t)s3 * ED + lane]);
    ax0 += x0 + x2;
    ax1 += x1 + x3;
    if (RBF && lane < NS) {
      float d0 = sdist[j], d1 = sdist[j + 1], d2 = sdist[j + 2], d3 = sdist[j + 3];
      float u0 = d0 - shift, u1 = d1 - shift, u2 = d2 - shift, u3 = d3 - shift;
      ar0 += __expf(-u0 * u0) + __expf(-u2 * u2);
      ar1 += __expf(-u1 * u1) + __expf(-u3 * u3);
    }
  }
  for (; j < e1; j++) {
    int s = ssink[j];
    ax0 += ubf2f((unsigned short)xqs[(size_t)s * ED + lane]);
    if (RBF && lane < NS) {
      float u = sdist[j] - shift;
      ar0 += __expf(-u * u);
    }
  }
  float accx = ax0 + ax1;
  if (RBF && lane < NS) mh[(size_t)node * 96 + lane] = (short)f2bf(ar0 + ar1);
  mh[(size_t)node * 96 + NS + lane] = (short)f2bf(accx);
}

// ---------------- batchnorm stats on bf16 planes (vectorized, 512 blocks) ----
template <int LD>
__global__ __launch_bounds__(256) void colstats_s16_kernel(const short* __restrict__ X,
                                                           float* __restrict__ P) {
  constexpr int CG = LD / 8;     // 8-col groups
  constexpr int RPB = 256 / CG;
  const int t = threadIdx.x;
  const int cg = t % CG, rin = t / CG;
  float s[8] = {0, 0, 0, 0, 0, 0, 0, 0}, q[8] = {0, 0, 0, 0, 0, 0, 0, 0};
  if (rin < RPB) {
    for (int r = blockIdx.x * RPB + rin; r < NN; r += gridDim.x * RPB) {
      union { uint4 v; short e[8]; } u;
      u.v = *(const uint4*)(X + (size_t)r * LD + cg * 8);
#pragma unroll
      for (int e = 0; e < 8; e++) {
        float f = ubf2f((unsigned short)u.e[e]);
        s[e] += f;
        q[e] += f * f;
      }
    }
  }
  __shared__ float sh[256][16];
#pragma unroll
  for (int e = 0; e < 8; e++) { sh[t][e] = s[e]; sh[t][8 + e] = q[e]; }
  __syncthreads();
  if (rin == 0) {
    for (int rr = 1; rr < RPB; rr++) {
      const float* o = sh[rr * CG + cg];
#pragma unroll
      for (int e = 0; e < 8; e++) { s[e] += o[e]; q[e] += o[8 + e]; }
    }
    float* Pb = P + blockIdx.x * 512;
#pragma unroll
    for (int e = 0; e < 8; e++) {
      Pb[cg * 8 + e] = s[e];
      Pb[256 + cg * 8 + e] = q[e];
    }
  }
}

// ---------------- batchnorm stats: stage 2 (one block per column) ------------
__global__ __launch_bounds__(256) void bnfinal2_kernel(const float* __restrict__ P, int nblk,
                                                       const float* __restrict__ g,
                                                       const float* __restrict__ b, int ncols,
                                                       float* __restrict__ na,
                                                       float* __restrict__ nb) {
  int c = blockIdx.x;
  int t = threadIdx.x;
  float s = 0.f, q = 0.f;
  for (int i = t; i < nblk; i += 256) {
    s += P[i * 512 + c];
    q += P[i * 512 + 256 + c];
  }
#pragma unroll
  for (int off = 32; off > 0; off >>= 1) {
    s += __shfl_down(s, off, 64);
    q += __shfl_down(q, off, 64);
  }
  __shared__ float ws[4], wq[4];
  if ((t & 63) == 0) { ws[t >> 6] = s; wq[t >> 6] = q; }
  __syncthreads();
  if (t == 0) {
    s = ws[0] + ws[1] + ws[2] + ws[3];
    q = wq[0] + wq[1] + wq[2] + wq[3];
    if (c < ncols) {
      float mean = s / (float)NN;
      float var = q / (float)NN - mean * mean;
      float a = g[c] * rsqrtf(var + 1e-5f);
      na[c] = a;
      nb[c] = b[c] - mean * a;
    } else {
      na[c] = 0.f;
      nb[c] = 0.f;
    }
  }
}

// ---------------- fused MLP kernel (packed-B, mixed terms, unrolled K) -------
template <bool READOUT>
__global__ __launch_bounds__(512, 4) void fused_kernel(
    const short* __restrict__ Agh, int glda,
    const short* __restrict__ W1p,
    const short* __restrict__ W2p, const short* __restrict__ W3p,
    const short* __restrict__ W4p,
    const float* __restrict__ b1, const float* __restrict__ b2,
    const float* __restrict__ b3, const float* __restrict__ b4,
    unsigned* __restrict__ xp, short* __restrict__ xq, short* __restrict__ xqs,
    int t, const float* __restrict__ w4ro, const int* __restrict__ mol,
    float* __restrict__ out) {
  __shared__ short ldsH[64 * SP + 16];
  const int tid = threadIdx.x;
  const int wave = tid >> 6, lane = tid & 63, ln = lane & 15, quad = lane >> 4;
  const int bm = blockIdx.x * 64;
  const int ntile = (wave < 5) ? 2 : 1;
  const int tile0 = (wave < 5) ? 2 * wave : wave + 5;  // 13 tiles of 16
  const int n0col = tile0 * 16;

  if (tid < 16) ldsH[64 * SP + tid] = 0;  // zero tail for row-63 k-overread

  f32x4 acc[4][2];

  // KB/KP compile-time -> full unroll lets the scheduler batch B bursts.
  auto layer = [&](auto ga_tag, auto terms_tag, auto kb_tag, auto kp_tag,
                   const short* __restrict__ Wp) {
    constexpr bool GA = decltype(ga_tag)::value;
    constexpr int TERMS = decltype(terms_tag)::value;
    constexpr int KB = decltype(kb_tag)::value;
    constexpr int KP = decltype(kp_tag)::value;
    (void)KB;
#pragma unroll
    for (int i = 0; i < 4; i++)
#pragma unroll
      for (int j = 0; j < 2; j++) acc[i][j] = (f32x4){0.f, 0.f, 0.f, 0.f};
#pragma unroll
    for (int k0 = 0; k0 < KP; k0 += 32) {
      const int kb = k0 >> 5;
      short8b ah[4], bh[2], bl[2];
#pragma unroll
      for (int i = 0; i < 4; i++) {
        int r = i * 16 + ln;
        if constexpr (GA)
          ah[i] = *(const short8b*)(Agh + (size_t)(bm + r) * glda + k0 + quad * 8);
        else
          ah[i] = *(const short8b*)(ldsH + r * SP + k0 + quad * 8);
      }
#pragma unroll
      for (int j = 0; j < 2; j++)
        if (j < ntile) {
          const short* bp = Wp + ((size_t)((tile0 + j) * KB + kb)) * 1024 + lane * 8;
          bh[j] = *(const short8b*)bp;
          if constexpr (TERMS == 2) bl[j] = *(const short8b*)(bp + 512);
        }
#pragma unroll
      for (int j = 0; j < 2; j++)
        if (j < ntile)
#pragma unroll
          for (int i = 0; i < 4; i++) {
            acc[i][j] = __builtin_amdgcn_mfma_f32_16x16x32_bf16(ah[i], bh[j], acc[i][j], 0, 0, 0);
            if constexpr (TERMS == 2)
              acc[i][j] =
                  __builtin_amdgcn_mfma_f32_16x16x32_bf16(ah[i], bl[j], acc[i][j], 0, 0, 0);
          }
    }
  };

  // epilogue: relu(acc+bias) -> hi plane; zero cols [208,216) of every row
  auto epi = [&](const float* __restrict__ bias) {
    __syncthreads();
#pragma unroll
    for (int i = 0; i < 4; i++)
#pragma unroll
      for (int j = 0; j < 2; j++)
        if (j < ntile)
#pragma unroll
          for (int r = 0; r < 4; r++) {
            int row = i * 16 + quad * 4 + r;
            int col = n0col + j * 16 + ln;
            float v = acc[i][j][r] + (col < HH ? bias[col] : 0.f);
            v = fmaxf(v, 0.f);
            ldsH[row * SP + col] = (short)f2bf(v);
          }
    // NaN guard: cols 208..215 (8 threads/row x 1 short, 512 thr = 64 rows)
    ldsH[(tid >> 3) * SP + 208 + (tid & 7)] = 0;
    __syncthreads();
  };

  using one_t = std::integral_constant<int, 1>;
  using two_t = std::integral_constant<int, 2>;

  if (!READOUT) {
    layer(std::true_type{}, two_t{}, std::integral_constant<int, 3>{},
          std::integral_constant<int, 96>{}, W1p);
    epi(b1);
    layer(std::false_type{}, one_t{}, std::integral_constant<int, 7>{},
          std::integral_constant<int, 224>{}, W2p);
    epi(b2);
    layer(std::false_type{}, one_t{}, std::integral_constant<int, 7>{},
          std::integral_constant<int, 224>{}, W3p);
    epi(b3);
    // ---- L4 (200->64): 2M x 4N wave split, packed B, 2-term ----
    const int wm4 = wave & 1, wn4 = wave >> 1;  // rows wm4*32.., col tile wn4
    f32x4 a4[2];
#pragma unroll
    for (int i = 0; i < 2; i++) a4[i] = (f32x4){0.f, 0.f, 0.f, 0.f};
#pragma unroll
    for (int k0 = 0; k0 < 224; k0 += 32) {
      const int kb = k0 >> 5;
      short8b ah[2], bh, bl;
#pragma unroll
      for (int i = 0; i < 2; i++) {
        int r = wm4 * 32 + i * 16 + ln;
        ah[i] = *(const short8b*)(ldsH + r * SP + k0 + quad * 8);
      }
      const short* bp = W4p + ((size_t)(wn4 * 7 + kb)) * 1024 + lane * 8;
      bh = *(const short8b*)bp;
      bl = *(const short8b*)(bp + 512);
#pragma unroll
      for (int i = 0; i < 2; i++) {
        a4[i] = __builtin_amdgcn_mfma_f32_16x16x32_bf16(ah[i], bh, a4[i], 0, 0, 0);
        a4[i] = __builtin_amdgcn_mfma_f32_16x16x32_bf16(ah[i], bl, a4[i], 0, 0, 0);
      }
    }
    // x-update: x[t+1] = x[t] + 0.1*(h3@W4 + b4); maintain row plane + slice plane
#pragma unroll
    for (int i = 0; i < 2; i++)
#pragma unroll
      for (int r = 0; r < 4; r++) {
        int grow = bm + wm4 * 32 + i * 16 + quad * 4 + r;
        int col = wn4 * 16 + ln;
        if (grow < NN) {
          float v = a4[i][r] + b4[col];
          size_t base = (size_t)grow * RD;
          float old = bfp2f(xp[base + (size_t)t * ED + col]);
          unsigned pk = packsplit(old + 0.1f * v);
          xp[base + (size_t)(t + 1) * ED + col] = pk;
          short h = (short)(pk & 0xffffu);
          xq[base + (size_t)(t + 1) * ED + col] = h;
          xqs[(size_t)(t + 1) * NN * ED + (size_t)grow * ED + col] = h;
        }
      }
  } else {
    layer(std::true_type{}, two_t{}, std::integral_constant<int, 8>{},
          std::integral_constant<int, 256>{}, W1p);
    epi(b1);
    layer(std::false_type{}, one_t{}, std::integral_constant<int, 7>{},
          std::integral_constant<int, 224>{}, W2p);
    epi(b2);
    layer(std::false_type{}, one_t{}, std::integral_constant<int, 7>{},
          std::integral_constant<int, 224>{}, W3p);
    epi(b3);
    // fused final layer (200->1) + molecule segment-sum: 8 threads per row
    int row = tid >> 3;
    int grow = bm + row;
    float s = 0.f;
    for (int c = (tid & 7); c < HH; c += 8)
      s += ubf2f((unsigned short)ldsH[row * SP + c]) * w4ro[c];
    s += __shfl_xor(s, 1, 64);
    s += __shfl_xor(s, 2, 64);
    s += __shfl_xor(s, 4, 64);
    if ((tid & 7) == 0 && grow < NN) atomicAdd(&out[mol[grow]], s + b4[0]);
  }
}

// ---------------- host launcher ----------------
extern "C" void kernel_launch(void* const* d_in, const int* in_sizes, int n_in,
                              void* d_out, int out_size, void* d_ws, size_t ws_size,
                              hipStream_t stream) {
  const int* z_i = (const int*)d_in[0];
  const int* e_src = (const int*)d_in[1];
  const int* e_snk = ((const int*)d_in[1]) + EE;
  const float* dist = (const float*)d_in[2];
  const int* mol = (const int*)d_in[3];
  const float* emb = (const float*)d_in[4];
  const float* up_bn_g = (const float*)d_in[5];
  const float* up_bn_b = (const float*)d_in[6];
  const float* up_w1 = (const float*)d_in[7];
  const float* up_b1 = (const float*)d_in[8];
  const float* up_w2 = (const float*)d_in[9];
  const float* up_b2 = (const float*)d_in[10];
  const float* up_w3 = (const float*)d_in[11];
  const float* up_b3 = (const float*)d_in[12];
  const float* up_w4 = (const float*)d_in[13];
  const float* up_b4 = (const float*)d_in[14];
  const float* ro_bn_g = (const float*)d_in[15];
  const float* ro_bn_b = (const float*)d_in[16];
  const float* ro_w1 = (const float*)d_in[17];
  const float* ro_b1 = (const float*)d_in[18];
  const float* ro_w2 = (const float*)d_in[19];
  const float* ro_b2 = (const float*)d_in[20];
  const float* ro_w3 = (const float*)d_in[21];
  const float* ro_b3 = (const float*)d_in[22];
  const float* ro_w4 = (const float*)d_in[23];
  const float* ro_b4 = (const float*)d_in[24];
  float* out = (float*)d_out;

  char* p = (char*)d_ws;
  auto alloc = [&](size_t bytes) {
    void* r = (void*)p;
    p += (bytes + 255) & ~(size_t)255;
    return r;
  };
  unsigned* x_p = (unsigned*)alloc((size_t)NN * RD * 4);     // fp32-equiv pair
  short* x_q = (short*)alloc((size_t)NP * RD * 2);           // x hi plane (row-major)
  short* x_qs = (short*)alloc((size_t)(TT + 1) * NN * ED * 2);  // x hi SLICE-major (gather)
  short* mh = (short*)alloc((size_t)NP * 96 * 2);            // raw m hi plane
  int* ssink = (int*)alloc((size_t)EE * 4);
  float* sdist = (float*)alloc((size_t)EE * 4);
  int* offs = (int*)alloc((size_t)(NN + 1) * 4);
  int* deg = (int*)alloc((size_t)NN * 4);
  int* cursor = (int*)alloc((size_t)NN * 4);
  int* Psum = (int*)alloc((size_t)SNB * 4);
  int* Poff = (int*)alloc((size_t)SNB * 4);
  float* P = (float*)alloc((size_t)NPB2 * 512 * 4);
  float* na = (float*)alloc(256 * 4);
  float* nb = (float*)alloc(256 * 4);
  float* b1c = (float*)alloc(208 * 4);
  // packed layer-1 (BN-scaled per pass / readout)
  short* w1sp = (short*)alloc((size_t)13 * 3 * 1024 * 2);
  short* r1sp = (short*)alloc((size_t)13 * 8 * 1024 * 2);
  // packed static weights
  short* w2p = (short*)alloc((size_t)TT * 13 * 7 * 1024 * 2);
  short* w3p = (short*)alloc((size_t)TT * 13 * 7 * 1024 * 2);
  short* w4p = (short*)alloc((size_t)TT * 4 * 7 * 1024 * 2);
  short* r2p = (short*)alloc((size_t)13 * 7 * 1024 * 2);
  short* r3p = (short*)alloc((size_t)13 * 7 * 1024 * 2);

  hipMemsetAsync(deg, 0, (size_t)NN * 4, stream);
  hipMemsetAsync(out, 0, (size_t)NMOL * 4, stream);

  WDs descs;
  descs.d[0] = {up_w2, w2p, HH, HH, 224, 208, TT};
  descs.d[1] = {up_w3, w3p, HH, HH, 224, 208, TT};
  descs.d[2] = {up_w4, w4p, HH, ED, 224, 64, TT};
  descs.d[3] = {ro_w2, r2p, HH, HH, 224, 208, 1};
  descs.d[4] = {ro_w3, r3p, HH, HH, 224, 208, 1};
  wprep_kernel<<<dim3(546, 5), 256, 0, stream>>>(descs);

  emb_kernel<<<(NN * ED + 255) / 256, 256, 0, stream>>>(z_i, emb, x_p, x_q, x_qs);
  hist_kernel<<<(EE + 255) / 256, 256, 0, stream>>>(e_src, deg);
  scanA_kernel<<<SNB, 256, 0, stream>>>(deg, Psum);
  scanB_kernel<<<1, 256, 0, stream>>>(Psum, Poff);
  scanC_kernel<<<SNB, 256, 0, stream>>>(deg, Poff, offs, cursor);
  scatter_kernel<<<(EE + 255) / 256, 256, 0, stream>>>(e_src, e_snk, dist, cursor, ssink, sdist);

  const int gM = NP / 64;  // 782

  for (int t = 0; t < TT; t++) {
    if (t == 0)
      gather_kernel<true><<<(NN + 3) / 4, 256, 0, stream>>>(
          offs, ssink, sdist, x_qs, mh);
    else
      gather_kernel<false><<<(NN + 3) / 4, 256, 0, stream>>>(
          offs, ssink, sdist, x_qs + (size_t)t * NN * ED, mh);
    colstats_s16_kernel<96><<<NPB2, 256, 0, stream>>>(mh, P);
    bnfinal2_kernel<<<256, 256, 0, stream>>>(P, NPB2, up_bn_g + t * MD, up_bn_b + t * MD, MD,
                                             na, nb);
    wscale_kernel<<<208, 256, 0, stream>>>(up_w1 + (size_t)t * MD * HH, na, nb,
                                           up_b1 + t * HH, MD, 96, w1sp, b1c);
    fused_kernel<false><<<gM, 512, 0, stream>>>(
        mh, 96, w1sp,
        w2p + (size_t)t * 13 * 7 * 1024, w3p + (size_t)t * 13 * 7 * 1024,
        w4p + (size_t)t * 4 * 7 * 1024,
        b1c, up_b2 + t * HH, up_b3 + t * HH, up_b4 + t * ED,
        x_p, x_q, x_qs, t, nullptr, nullptr, nullptr);
  }

  colstats_s16_kernel<256><<<NPB2, 256, 0, stream>>>(x_q, P);
  bnfinal2_kernel<<<256, 256, 0, stream>>>(P, NPB2, ro_bn_g, ro_bn_b, RD, na, nb);
  wscale_kernel<<<208, 256, 0, stream>>>(ro_w1, na, nb, ro_b1, RD, 256, r1sp, b1c);
  fused_kernel<true><<<gM, 512, 0, stream>>>(
      x_q, 256, r1sp,
      r2p, r3p, nullptr,
      b1c, ro_b2, ro_b3, ro_b4,
      nullptr, nullptr, nullptr, 0, ro_w4, mol, out);

  (void)in_sizes; (void)n_in; (void)out_size; (void)ws_size;
}

// Round 23
// 594.574 us; speedup vs baseline: 1.4590x; 1.0103x over previous
//
#include <hip/hip_runtime.h>
#include <hip/hip_bf16.h>
#include <type_traits>

#define NN 50000
#define NP 50048   // NN padded to 64*782
#define EE 800000
#define TT 3
#define ED 64
#define NS 23
#define MD 87
#define HH 200
#define NMOL 2048
#define RD 256

#define SP 216     // LDS act hi-plane stride (shorts)
#define NPB2 512   // colstats partial blocks
#define SNB ((NN + 255) / 256)  // 196 scan blocks

typedef __attribute__((ext_vector_type(8))) short short8b;
typedef __attribute__((ext_vector_type(4))) short short4b;
typedef __attribute__((ext_vector_type(4))) float f32x4;

// ---- bf16 helpers ----
__device__ __forceinline__ unsigned short f2bf(float f) {
  unsigned u = __float_as_uint(f);
  return (unsigned short)((u + 0x7fffu + ((u >> 16) & 1u)) >> 16);
}
__device__ __forceinline__ float ubf2f(unsigned short h) {
  return __uint_as_float(((unsigned)h) << 16);
}
// interleaved pair in one u32: low16 = hi-bf16, high16 = lo-bf16 (fp32-equivalent)
__device__ __forceinline__ float bfp2f(unsigned p) {
  return __uint_as_float(p << 16) + __uint_as_float(p & 0xffff0000u);
}
__device__ __forceinline__ unsigned packsplit(float v) {
  unsigned short h = f2bf(v);
  unsigned short l = f2bf(v - ubf2f(h));
  return (unsigned)h | ((unsigned)l << 16);
}

// ---------------- weight prep: fp32 [T][K][N] -> PACKED fragment-major planes -----
// Packed layout: per (tile of 16 n-rows, kblk of 32 cols): 1024 shorts =
// [512 hi][512 lo], lane-linear (slot = lane*8+e, lane = quad*16+ln,
// n = tile*16+ln, k = kblk*32+quad*8+e). B-frag load = ONE coalesced 1KB burst.
struct WD { const float* src; short* dst; int K, N, Kpad, Npad, T; };
struct WDs { WD d[5]; };

__global__ __launch_bounds__(256) void wprep_kernel(WDs W) {
  WD w = W.d[blockIdx.y];
  int KB = w.Kpad >> 5, NT = w.Npad >> 4;
  int per = w.Npad * w.Kpad;  // == NT*KB*512
  int total = w.T * per;
  for (int idx = blockIdx.x * 256 + threadIdx.x; idx < total; idx += gridDim.x * 256) {
    int t = idx / per;
    int r = idx - t * per;
    int e = r & 7, lane = (r >> 3) & 63;
    int blk = r >> 9;
    int kb = blk % KB, tile = blk / KB;
    int ln = lane & 15, quad = lane >> 4;
    int n = tile * 16 + ln, k = kb * 32 + quad * 8 + e;
    float v = 0.f;
    if (k < w.K && n < w.N) v = w.src[((size_t)t * w.K + k) * w.N + n];
    unsigned short h = f2bf(v);
    unsigned short l = f2bf(v - ubf2f(h));
    size_t base = ((size_t)(t * NT + tile) * KB + kb) * 1024;
    w.dst[base + lane * 8 + e] = (short)h;
    w.dst[base + 512 + lane * 8 + e] = (short)l;
  }
}

// ---------------- BN-folded layer-1 weight scale (packed output) ----------------
// R21 lesson: keep the P reduction in bnfinal2 (single pass over P).
__global__ __launch_bounds__(256) void wscale_kernel(const float* __restrict__ wsrc,
                                                     const float* __restrict__ na,
                                                     const float* __restrict__ nb,
                                                     const float* __restrict__ bsrc,
                                                     int K, int Kpad,
                                                     short* __restrict__ wsp,
                                                     float* __restrict__ bc) {
  int n = blockIdx.x;   // 0..207
  int k = threadIdx.x;  // 0..255
  int KB = Kpad >> 5;
  int tile = n >> 4, ln = n & 15;
  float contrib = 0.f;
  if (k < Kpad) {
    float v = 0.f;
    if (n < HH && k < K) {
      float w = wsrc[(size_t)k * HH + n];
      v = na[k] * w;
      contrib = nb[k] * w;
    }
    unsigned short h = f2bf(v);
    unsigned short l = f2bf(v - ubf2f(h));
    int kb = k >> 5, quad = (k & 31) >> 3, e = k & 7;
    int lane = quad * 16 + ln;
    size_t base = ((size_t)tile * KB + kb) * 1024;
    wsp[base + lane * 8 + e] = (short)h;
    wsp[base + 512 + lane * 8 + e] = (short)l;
  }
  __shared__ float sh[256];
  sh[k] = contrib;
  __syncthreads();
  for (int off = 128; off > 0; off >>= 1) {
    if (k < off) sh[k] += sh[k + off];
    __syncthreads();
  }
  if (k == 0) bc[n] = (n < HH ? bsrc[n] : 0.f) + sh[0];
}

// ---------------- embedding -> x slice 0 (pair + slice plane) ----------------
__global__ __launch_bounds__(256) void emb_kernel(const int* __restrict__ z,
                                                  const float* __restrict__ emb,
                                                  unsigned* __restrict__ xp,
                                                  short* __restrict__ xqs) {
  int idx = blockIdx.x * 256 + threadIdx.x;
  if (idx >= NN * ED) return;
  int i = idx >> 6, d = idx & 63;
  unsigned pk = packsplit(emb[z[i] * ED + d]);
  xp[(size_t)i * RD + d] = pk;
  xqs[(size_t)i * ED + d] = (short)(pk & 0xffffu);  // slice 0
}

// ---------------- CSR build ----------------
__global__ __launch_bounds__(256) void hist_kernel(const int* __restrict__ src,
                                                   int* __restrict__ deg) {
  int e = blockIdx.x * 256 + threadIdx.x;
  if (e < EE) atomicAdd(&deg[src[e]], 1);
}

// 3-stage parallel exclusive scan of deg[0..NN)
__global__ __launch_bounds__(256) void scanA_kernel(const int* __restrict__ deg,
                                                    int* __restrict__ Psum) {
  int i = blockIdx.x * 256 + threadIdx.x;
  int v = (i < NN) ? deg[i] : 0;
#pragma unroll
  for (int off = 32; off > 0; off >>= 1) v += __shfl_down(v, off, 64);
  __shared__ int ws[4];
  if ((threadIdx.x & 63) == 0) ws[threadIdx.x >> 6] = v;
  __syncthreads();
  if (threadIdx.x == 0) Psum[blockIdx.x] = ws[0] + ws[1] + ws[2] + ws[3];
}

__global__ __launch_bounds__(256) void scanB_kernel(const int* __restrict__ Psum,
                                                    int* __restrict__ Poff) {
  __shared__ int sh[256];
  int t = threadIdx.x;
  int v = (t < SNB) ? Psum[t] : 0;
  sh[t] = v;
  __syncthreads();
  for (int off = 1; off < 256; off <<= 1) {
    int u = (t >= off) ? sh[t - off] : 0;
    __syncthreads();
    sh[t] += u;
    __syncthreads();
  }
  if (t < SNB) Poff[t] = sh[t] - v;  // exclusive
}

__global__ __launch_bounds__(256) void scanC_kernel(const int* __restrict__ deg,
                                                    const int* __restrict__ Poff,
                                                    int* __restrict__ offs,
                                                    int* __restrict__ cursor) {
  __shared__ int sh[256];
  int t = threadIdx.x;
  int i = blockIdx.x * 256 + t;
  int v = (i < NN) ? deg[i] : 0;
  sh[t] = v;
  __syncthreads();
  for (int off = 1; off < 256; off <<= 1) {
    int u = (t >= off) ? sh[t - off] : 0;
    __syncthreads();
    sh[t] += u;
    __syncthreads();
  }
  int excl = Poff[blockIdx.x] + sh[t] - v;
  if (i < NN) {
    offs[i] = excl;
    cursor[i] = excl;
    if (i == NN - 1) offs[NN] = excl + v;
  }
}

__global__ __launch_bounds__(256) void scatter_kernel(const int* __restrict__ src,
                                                      const int* __restrict__ snk,
                                                      const float* __restrict__ dist,
                                                      int* __restrict__ cursor,
                                                      int* __restrict__ ssink,
                                                      float* __restrict__ sdist) {
  int e = blockIdx.x * 256 + threadIdx.x;
  if (e >= EE) return;
  int p = atomicAdd(&cursor[src[e]], 1);
  ssink[p] = snk[e];
  sdist[p] = dist[e];
}

// ---------------- message gather: one wave per node ----------------
// Reads SLICE-MAJOR xqs (6.4 MB working set -> L2-resident). RBF sums
// (m cols 0..22) are pass-invariant: computed only at t=0.
template <bool RBF>
__global__ __launch_bounds__(256) void gather_kernel(const int* __restrict__ offs,
                                                     const int* __restrict__ ssink,
                                                     const float* __restrict__ sdist,
                                                     const short* __restrict__ xqs,
                                                     short* __restrict__ mh) {
  int node = blockIdx.x * 4 + (threadIdx.x >> 6);
  int lane = threadIdx.x & 63;
  if (node >= NN) return;
  float shift = (float)(0.8 + 0.1 * (double)lane);
  int e0 = offs[node], e1 = offs[node + 1];
  float ax0 = 0.f, ax1 = 0.f, ar0 = 0.f, ar1 = 0.f;
  int j = e0;
  for (; j + 4 <= e1; j += 4) {
    int s0 = ssink[j], s1 = ssink[j + 1], s2 = ssink[j + 2], s3 = ssink[j + 3];
    float x0 = ubf2f((unsigned short)xqs[(size_t)s0 * ED + lane]);
    float x1 = ubf2f((unsigned short)xqs[(size_t)s1 * ED + lane]);
    float x2 = ubf2f((unsigned short)xqs[(size_t)s2 * ED + lane]);
    float x3 = ubf2f((unsigned short)xqs[(size_t)s3 * ED + lane]);
    ax0 += x0 + x2;
    ax1 += x1 + x3;
    if (RBF && lane < NS) {
      float d0 = sdist[j], d1 = sdist[j + 1], d2 = sdist[j + 2], d3 = sdist[j + 3];
      float u0 = d0 - shift, u1 = d1 - shift, u2 = d2 - shift, u3 = d3 - shift;
      ar0 += __expf(-u0 * u0) + __expf(-u2 * u2);
      ar1 += __expf(-u1 * u1) + __expf(-u3 * u3);
    }
  }
  for (; j < e1; j++) {
    int s = ssink[j];
    ax0 += ubf2f((unsigned short)xqs[(size_t)s * ED + lane]);
    if (RBF && lane < NS) {
      float u = sdist[j] - shift;
      ar0 += __expf(-u * u);
    }
  }
  float accx = ax0 + ax1;
  if (RBF && lane < NS) mh[(size_t)node * 96 + lane] = (short)f2bf(ar0 + ar1);
  mh[(size_t)node * 96 + NS + lane] = (short)f2bf(accx);
}

// ---------------- batchnorm stats on bf16 planes (vectorized, 512 blocks) ----
template <int LD>
__global__ __launch_bounds__(256) void colstats_s16_kernel(const short* __restrict__ X,
                                                           float* __restrict__ P) {
  constexpr int CG = LD / 8;     // 8-col groups
  constexpr int RPB = 256 / CG;
  const int t = threadIdx.x;
  const int cg = t % CG, rin = t / CG;
  float s[8] = {0, 0, 0, 0, 0, 0, 0, 0}, q[8] = {0, 0, 0, 0, 0, 0, 0, 0};
  if (rin < RPB) {
    for (int r = blockIdx.x * RPB + rin; r < NN; r += gridDim.x * RPB) {
      union { uint4 v; short e[8]; } u;
      u.v = *(const uint4*)(X + (size_t)r * LD + cg * 8);
#pragma unroll
      for (int e = 0; e < 8; e++) {
        float f = ubf2f((unsigned short)u.e[e]);
        s[e] += f;
        q[e] += f * f;
      }
    }
  }
  __shared__ float sh[256][16];
#pragma unroll
  for (int e = 0; e < 8; e++) { sh[t][e] = s[e]; sh[t][8 + e] = q[e]; }
  __syncthreads();
  if (rin == 0) {
    for (int rr = 1; rr < RPB; rr++) {
      const float* o = sh[rr * CG + cg];
#pragma unroll
      for (int e = 0; e < 8; e++) { s[e] += o[e]; q[e] += o[8 + e]; }
    }
    float* Pb = P + blockIdx.x * 512;
#pragma unroll
    for (int e = 0; e < 8; e++) {
      Pb[cg * 8 + e] = s[e];
      Pb[256 + cg * 8 + e] = q[e];
    }
  }
}

// ---------------- readout stats over SLICE-MAJOR x (virtual 256 cols) --------
__global__ __launch_bounds__(256) void colstats_xqs_kernel(const short* __restrict__ xqs,
                                                           float* __restrict__ P) {
  constexpr int CG = 32;   // 8-col groups over 256 virtual cols
  constexpr int RPB = 8;
  const int t = threadIdx.x;
  const int cg = t % CG, rin = t / CG;
  const int slice = cg >> 3, off = (cg & 7) * 8;
  const short* base = xqs + (size_t)slice * NN * ED + off;
  float s[8] = {0, 0, 0, 0, 0, 0, 0, 0}, q[8] = {0, 0, 0, 0, 0, 0, 0, 0};
  for (int r = blockIdx.x * RPB + rin; r < NN; r += gridDim.x * RPB) {
    union { uint4 v; short e[8]; } u;
    u.v = *(const uint4*)(base + (size_t)r * ED);
#pragma unroll
    for (int e = 0; e < 8; e++) {
      float f = ubf2f((unsigned short)u.e[e]);
      s[e] += f;
      q[e] += f * f;
    }
  }
  __shared__ float sh[256][16];
#pragma unroll
  for (int e = 0; e < 8; e++) { sh[t][e] = s[e]; sh[t][8 + e] = q[e]; }
  __syncthreads();
  if (rin == 0) {
    for (int rr = 1; rr < RPB; rr++) {
      const float* o = sh[rr * CG + cg];
#pragma unroll
      for (int e = 0; e < 8; e++) { s[e] += o[e]; q[e] += o[8 + e]; }
    }
    float* Pb = P + blockIdx.x * 512;
#pragma unroll
    for (int e = 0; e < 8; e++) {
      Pb[cg * 8 + e] = s[e];
      Pb[256 + cg * 8 + e] = q[e];
    }
  }
}

// ---------------- batchnorm stats: stage 2 (one block per column) ------------
__global__ __launch_bounds__(256) void bnfinal2_kernel(const float* __restrict__ P, int nblk,
                                                       const float* __restrict__ g,
                                                       const float* __restrict__ b, int ncols,
                                                       float* __restrict__ na,
                                                       float* __restrict__ nb) {
  int c = blockIdx.x;
  int t = threadIdx.x;
  float s = 0.f, q = 0.f;
  for (int i = t; i < nblk; i += 256) {
    s += P[i * 512 + c];
    q += P[i * 512 + 256 + c];
  }
#pragma unroll
  for (int off = 32; off > 0; off >>= 1) {
    s += __shfl_down(s, off, 64);
    q += __shfl_down(q, off, 64);
  }
  __shared__ float ws[4], wq[4];
  if ((t & 63) == 0) { ws[t >> 6] = s; wq[t >> 6] = q; }
  __syncthreads();
  if (t == 0) {
    s = ws[0] + ws[1] + ws[2] + ws[3];
    q = wq[0] + wq[1] + wq[2] + wq[3];
    if (c < ncols) {
      float mean = s / (float)NN;
      float var = q / (float)NN - mean * mean;
      float a = g[c] * rsqrtf(var + 1e-5f);
      na[c] = a;
      nb[c] = b[c] - mean * a;
    } else {
      na[c] = 0.f;
      nb[c] = 0.f;
    }
  }
}

// ---------------- fused MLP kernel (packed-B, mixed terms, unrolled K) -------
// READOUT L1 reads A from SLICE-MAJOR xqs (k-blocks of 32 never straddle the
// 64-wide slices). Pad-row overreads hit adjacent finite buffers: garbage A
// rows only affect discarded C rows (NOT the R10 NaN-B hazard; 0xAA is finite).
template <bool READOUT>
__global__ __launch_bounds__(512, 4) void fused_kernel(
    const short* __restrict__ Agh, int glda,
    const short* __restrict__ W1p,
    const short* __restrict__ W2p, const short* __restrict__ W3p,
    const short* __restrict__ W4p,
    const float* __restrict__ b1, const float* __restrict__ b2,
    const float* __restrict__ b3, const float* __restrict__ b4,
    unsigned* __restrict__ xp, short* __restrict__ xqs,
    int t, const float* __restrict__ w4ro, const int* __restrict__ mol,
    float* __restrict__ out) {
  __shared__ short ldsH[64 * SP + 16];
  const int tid = threadIdx.x;
  const int wave = tid >> 6, lane = tid & 63, ln = lane & 15, quad = lane >> 4;
  const int bm = blockIdx.x * 64;
  const int ntile = (wave < 5) ? 2 : 1;
  const int tile0 = (wave < 5) ? 2 * wave : wave + 5;  // 13 tiles of 16
  const int n0col = tile0 * 16;

  if (tid < 16) ldsH[64 * SP + tid] = 0;  // zero tail for row-63 k-overread

  f32x4 acc[4][2];

  // KB/KP compile-time -> full unroll lets the scheduler batch B bursts.
  auto layer = [&](auto ga_tag, auto sliced_tag, auto terms_tag, auto kb_tag,
                   auto kp_tag, const short* __restrict__ Wp) {
    constexpr bool GA = decltype(ga_tag)::value;
    constexpr bool SLICED = decltype(sliced_tag)::value;
    constexpr int TERMS = decltype(terms_tag)::value;
    constexpr int KB = decltype(kb_tag)::value;
    constexpr int KP = decltype(kp_tag)::value;
    (void)KB;
#pragma unroll
    for (int i = 0; i < 4; i++)
#pragma unroll
      for (int j = 0; j < 2; j++) acc[i][j] = (f32x4){0.f, 0.f, 0.f, 0.f};
#pragma unroll
    for (int k0 = 0; k0 < KP; k0 += 32) {
      const int kb = k0 >> 5;
      short8b ah[4], bh[2], bl[2];
#pragma unroll
      for (int i = 0; i < 4; i++) {
        int r = i * 16 + ln;
        if constexpr (GA && SLICED)
          ah[i] = *(const short8b*)(Agh + (size_t)(k0 >> 6) * ((size_t)NN * ED) +
                                    (size_t)(bm + r) * ED + (k0 & 63) + quad * 8);
        else if constexpr (GA)
          ah[i] = *(const short8b*)(Agh + (size_t)(bm + r) * glda + k0 + quad * 8);
        else
          ah[i] = *(const short8b*)(ldsH + r * SP + k0 + quad * 8);
      }
#pragma unroll
      for (int j = 0; j < 2; j++)
        if (j < ntile) {
          const short* bp = Wp + ((size_t)((tile0 + j) * KB + kb)) * 1024 + lane * 8;
          bh[j] = *(const short8b*)bp;
          if constexpr (TERMS == 2) bl[j] = *(const short8b*)(bp + 512);
        }
#pragma unroll
      for (int j = 0; j < 2; j++)
        if (j < ntile)
#pragma unroll
          for (int i = 0; i < 4; i++) {
            acc[i][j] = __builtin_amdgcn_mfma_f32_16x16x32_bf16(ah[i], bh[j], acc[i][j], 0, 0, 0);
            if constexpr (TERMS == 2)
              acc[i][j] =
                  __builtin_amdgcn_mfma_f32_16x16x32_bf16(ah[i], bl[j], acc[i][j], 0, 0, 0);
          }
    }
  };

  // epilogue: relu(acc+bias) -> hi plane; zero cols [208,216) of every row
  auto epi = [&](const float* __restrict__ bias) {
    __syncthreads();
#pragma unroll
    for (int i = 0; i < 4; i++)
#pragma unroll
      for (int j = 0; j < 2; j++)
        if (j < ntile)
#pragma unroll
          for (int r = 0; r < 4; r++) {
            int row = i * 16 + quad * 4 + r;
            int col = n0col + j * 16 + ln;
            float v = acc[i][j][r] + (col < HH ? bias[col] : 0.f);
            v = fmaxf(v, 0.f);
            ldsH[row * SP + col] = (short)f2bf(v);
          }
    // NaN guard: cols 208..215 (8 threads/row x 1 short, 512 thr = 64 rows)
    ldsH[(tid >> 3) * SP + 208 + (tid & 7)] = 0;
    __syncthreads();
  };

  using one_t = std::integral_constant<int, 1>;
  using two_t = std::integral_constant<int, 2>;
  using F = std::false_type;
  using T = std::true_type;

  if (!READOUT) {
    layer(T{}, F{}, two_t{}, std::integral_constant<int, 3>{},
          std::integral_constant<int, 96>{}, W1p);
    epi(b1);
    layer(F{}, F{}, one_t{}, std::integral_constant<int, 7>{},
          std::integral_constant<int, 224>{}, W2p);
    epi(b2);
    layer(F{}, F{}, one_t{}, std::integral_constant<int, 7>{},
          std::integral_constant<int, 224>{}, W3p);
    epi(b3);
    // ---- L4 (200->64): 2M x 4N wave split, packed B, 2-term ----
    const int wm4 = wave & 1, wn4 = wave >> 1;  // rows wm4*32.., col tile wn4
    f32x4 a4[2];
#pragma unroll
    for (int i = 0; i < 2; i++) a4[i] = (f32x4){0.f, 0.f, 0.f, 0.f};
#pragma unroll
    for (int k0 = 0; k0 < 224; k0 += 32) {
      const int kb = k0 >> 5;
      short8b ah[2], bh, bl;
#pragma unroll
      for (int i = 0; i < 2; i++) {
        int r = wm4 * 32 + i * 16 + ln;
        ah[i] = *(const short8b*)(ldsH + r * SP + k0 + quad * 8);
      }
      const short* bp = W4p + ((size_t)(wn4 * 7 + kb)) * 1024 + lane * 8;
      bh = *(const short8b*)bp;
      bl = *(const short8b*)(bp + 512);
#pragma unroll
      for (int i = 0; i < 2; i++) {
        a4[i] = __builtin_amdgcn_mfma_f32_16x16x32_bf16(ah[i], bh, a4[i], 0, 0, 0);
        a4[i] = __builtin_amdgcn_mfma_f32_16x16x32_bf16(ah[i], bl, a4[i], 0, 0, 0);
      }
    }
    // x-update: x[t+1] = x[t] + 0.1*(h3@W4 + b4); maintain pair + slice plane
#pragma unroll
    for (int i = 0; i < 2; i++)
#pragma unroll
      for (int r = 0; r < 4; r++) {
        int grow = bm + wm4 * 32 + i * 16 + quad * 4 + r;
        int col = wn4 * 16 + ln;
        if (grow < NN) {
          float v = a4[i][r] + b4[col];
          size_t base = (size_t)grow * RD;
          float old = bfp2f(xp[base + (size_t)t * ED + col]);
          unsigned pk = packsplit(old + 0.1f * v);
          xp[base + (size_t)(t + 1) * ED + col] = pk;
          xqs[(size_t)(t + 1) * NN * ED + (size_t)grow * ED + col] =
              (short)(pk & 0xffffu);
        }
      }
  } else {
    layer(T{}, T{}, two_t{}, std::integral_constant<int, 8>{},
          std::integral_constant<int, 256>{}, W1p);
    epi(b1);
    layer(F{}, F{}, one_t{}, std::integral_constant<int, 7>{},
          std::integral_constant<int, 224>{}, W2p);
    epi(b2);
    layer(F{}, F{}, one_t{}, std::integral_constant<int, 7>{},
          std::integral_constant<int, 224>{}, W3p);
    epi(b3);
    // fused final layer (200->1) + molecule segment-sum: 8 threads per row
    int row = tid >> 3;
    int grow = bm + row;
    float s = 0.f;
    for (int c = (tid & 7); c < HH; c += 8)
      s += ubf2f((unsigned short)ldsH[row * SP + c]) * w4ro[c];
    s += __shfl_xor(s, 1, 64);
    s += __shfl_xor(s, 2, 64);
    s += __shfl_xor(s, 4, 64);
    if ((tid & 7) == 0 && grow < NN) atomicAdd(&out[mol[grow]], s + b4[0]);
  }
}

// ---------------- host launcher ----------------
extern "C" void kernel_launch(void* const* d_in, const int* in_sizes, int n_in,
                              void* d_out, int out_size, void* d_ws, size_t ws_size,
                              hipStream_t stream) {
  const int* z_i = (const int*)d_in[0];
  const int* e_src = (const int*)d_in[1];
  const int* e_snk = ((const int*)d_in[1]) + EE;
  const float* dist = (const float*)d_in[2];
  const int* mol = (const int*)d_in[3];
  const float* emb = (const float*)d_in[4];
  const float* up_bn_g = (const float*)d_in[5];
  const float* up_bn_b = (const float*)d_in[6];
  const float* up_w1 = (const float*)d_in[7];
  const float* up_b1 = (const float*)d_in[8];
  const float* up_w2 = (const float*)d_in[9];
  const float* up_b2 = (const float*)d_in[10];
  const float* up_w3 = (const float*)d_in[11];
  const float* up_b3 = (const float*)d_in[12];
  const float* up_w4 = (const float*)d_in[13];
  const float* up_b4 = (const float*)d_in[14];
  const float* ro_bn_g = (const float*)d_in[15];
  const float* ro_bn_b = (const float*)d_in[16];
  const float* ro_w1 = (const float*)d_in[17];
  const float* ro_b1 = (const float*)d_in[18];
  const float* ro_w2 = (const float*)d_in[19];
  const float* ro_b2 = (const float*)d_in[20];
  const float* ro_w3 = (const float*)d_in[21];
  const float* ro_b3 = (const float*)d_in[22];
  const float* ro_w4 = (const float*)d_in[23];
  const float* ro_b4 = (const float*)d_in[24];
  float* out = (float*)d_out;

  char* p = (char*)d_ws;
  auto alloc = [&](size_t bytes) {
    void* r = (void*)p;
    p += (bytes + 255) & ~(size_t)255;
    return r;
  };
  unsigned* x_p = (unsigned*)alloc((size_t)NN * RD * 4);        // fp32-equiv pair
  short* x_qs = (short*)alloc((size_t)(TT + 1) * NN * ED * 2);  // x hi SLICE-major
  short* mh = (short*)alloc((size_t)NP * 96 * 2);               // raw m hi plane
  int* ssink = (int*)alloc((size_t)EE * 4);
  float* sdist = (float*)alloc((size_t)EE * 4);
  int* offs = (int*)alloc((size_t)(NN + 1) * 4);
  int* deg = (int*)alloc((size_t)NN * 4);
  int* cursor = (int*)alloc((size_t)NN * 4);
  int* Psum = (int*)alloc((size_t)SNB * 4);
  int* Poff = (int*)alloc((size_t)SNB * 4);
  float* P = (float*)alloc((size_t)NPB2 * 512 * 4);
  float* na = (float*)alloc(256 * 4);
  float* nb = (float*)alloc(256 * 4);
  float* b1c = (float*)alloc(208 * 4);
  // packed layer-1 (BN-scaled per pass / readout)
  short* w1sp = (short*)alloc((size_t)13 * 3 * 1024 * 2);
  short* r1sp = (short*)alloc((size_t)13 * 8 * 1024 * 2);
  // packed static weights
  short* w2p = (short*)alloc((size_t)TT * 13 * 7 * 1024 * 2);
  short* w3p = (short*)alloc((size_t)TT * 13 * 7 * 1024 * 2);
  short* w4p = (short*)alloc((size_t)TT * 4 * 7 * 1024 * 2);
  short* r2p = (short*)alloc((size_t)13 * 7 * 1024 * 2);
  short* r3p = (short*)alloc((size_t)13 * 7 * 1024 * 2);

  hipMemsetAsync(deg, 0, (size_t)NN * 4, stream);
  hipMemsetAsync(out, 0, (size_t)NMOL * 4, stream);

  WDs descs;
  descs.d[0] = {up_w2, w2p, HH, HH, 224, 208, TT};
  descs.d[1] = {up_w3, w3p, HH, HH, 224, 208, TT};
  descs.d[2] = {up_w4, w4p, HH, ED, 224, 64, TT};
  descs.d[3] = {ro_w2, r2p, HH, HH, 224, 208, 1};
  descs.d[4] = {ro_w3, r3p, HH, HH, 224, 208, 1};
  wprep_kernel<<<dim3(546, 5), 256, 0, stream>>>(descs);

  emb_kernel<<<(NN * ED + 255) / 256, 256, 0, stream>>>(z_i, emb, x_p, x_qs);
  hist_kernel<<<(EE + 255) / 256, 256, 0, stream>>>(e_src, deg);
  scanA_kernel<<<SNB, 256, 0, stream>>>(deg, Psum);
  scanB_kernel<<<1, 256, 0, stream>>>(Psum, Poff);
  scanC_kernel<<<SNB, 256, 0, stream>>>(deg, Poff, offs, cursor);
  scatter_kernel<<<(EE + 255) / 256, 256, 0, stream>>>(e_src, e_snk, dist, cursor, ssink, sdist);

  const int gM = NP / 64;  // 782

  for (int t = 0; t < TT; t++) {
    if (t == 0)
      gather_kernel<true><<<(NN + 3) / 4, 256, 0, stream>>>(
          offs, ssink, sdist, x_qs, mh);
    else
      gather_kernel<false><<<(NN + 3) / 4, 256, 0, stream>>>(
          offs, ssink, sdist, x_qs + (size_t)t * NN * ED, mh);
    colstats_s16_kernel<96><<<NPB2, 256, 0, stream>>>(mh, P);
    bnfinal2_kernel<<<256, 256, 0, stream>>>(P, NPB2, up_bn_g + t * MD, up_bn_b + t * MD, MD,
                                             na, nb);
    wscale_kernel<<<208, 256, 0, stream>>>(up_w1 + (size_t)t * MD * HH, na, nb,
                                           up_b1 + t * HH, MD, 96, w1sp, b1c);
    fused_kernel<false><<<gM, 512, 0, stream>>>(
        mh, 96, w1sp,
        w2p + (size_t)t * 13 * 7 * 1024, w3p + (size_t)t * 13 * 7 * 1024,
        w4p + (size_t)t * 4 * 7 * 1024,
        b1c, up_b2 + t * HH, up_b3 + t * HH, up_b4 + t * ED,
        x_p, x_qs, t, nullptr, nullptr, nullptr);
  }

  colstats_xqs_kernel<<<NPB2, 256, 0, stream>>>(x_qs, P);
  bnfinal2_kernel<<<256, 256, 0, stream>>>(P, NPB2, ro_bn_g, ro_bn_b, RD, na, nb);
  wscale_kernel<<<208, 256, 0, stream>>>(ro_w1, na, nb, ro_b1, RD, 256, r1sp, b1c);
  fused_kernel<true><<<gM, 512, 0, stream>>>(
      x_qs, 0, r1sp,
      r2p, r3p, nullptr,
      b1c, ro_b2, ro_b3, ro_b4,
      nullptr, nullptr, 0, ro_w4, mol, out);

  (void)in_sizes; (void)n_in; (void)out_size; (void)ws_size;
}